// Round 2
// baseline (125.377 us; speedup 1.0000x reference)
//
#include <hip/hip_runtime.h>
#include <hip/hip_bf16.h>
#include <stdint.h>

// PSM cosine cost volume, MI355X (gfx950).
// out[b,d,h,w] = (1/C) * sum_c L[b,c,h,w] * R[b,c,h,w-d],  0 where w<d.
// Computed as banded Gram matrix M[w',w] = sum_c R[c,w'] L[c,w] via bf16 MFMA,
// band d = w-w' in [0,48). One block per (b,h,half-row).

#define B_ 4
#define C_ 512
#define H_ 96
#define W_ 312
#define D_ 48
#define HW_ (H_ * W_)      // 29952
#define CHW_ (C_ * HW_)

#define KC 64              // staged c per chunk
#define NCHUNK (C_ / KC)   // 8
#define HALFW 156          // output w span per block (2 * 156 = 312)
#define LCOLS 160          // staged L columns (10 N-tiles of 16)
#define RCOLS 208          // staged R columns ([wb-48, wb+160))
#define PITCH 128          // LDS row pitch bytes (64 bf16 = KC)
#define LBYTES (LCOLS * PITCH)          // 20480
#define RBYTES (RCOLS * PITCH)          // 26624
#define SMEM_BYTES (LBYTES + RBYTES)    // 47104 < 64 KiB

typedef __bf16 bf16x8 __attribute__((ext_vector_type(8)));
typedef float  f32x4  __attribute__((ext_vector_type(4)));

__device__ __forceinline__ uint32_t pack2_bf16(float a, float b) {
    // round-to-nearest-even f32 -> bf16, packed (a = low half = even c)
    uint32_t ua = __builtin_bit_cast(uint32_t, a);
    uint32_t ub = __builtin_bit_cast(uint32_t, b);
    ua += 0x7FFFu + ((ua >> 16) & 1u);
    ub += 0x7FFFu + ((ub >> 16) & 1u);
    return (ua >> 16) | (ub & 0xFFFF0000u);
}

__global__ __launch_bounds__(512, 4)
void psm_cost_volume(const float* __restrict__ lf,
                     const float* __restrict__ rf,
                     float* __restrict__ out) {
    const int half = blockIdx.x;        // 0,1
    const int h    = blockIdx.y;
    const int b    = blockIdx.z;
    const int wb   = half * HALFW;
    const int tid  = threadIdx.x;
    const int lane = tid & 63;
    const int wave = tid >> 6;          // 8 waves
    const int l15  = lane & 15;
    const int l4   = lane >> 4;

    extern __shared__ char smem[];
    // [0, LBYTES)          : L tile,  [w_local][c] bf16, XOR-swizzled 16B slots
    // [LBYTES, +RBYTES)    : R tile,  [w'_local][c] bf16, same swizzle
    // epilogue reuses [0, D_*HALFW*4) as f32 out staging

    const float* lbase = lf + (size_t)b * CHW_ + (size_t)h * W_;
    const float* rbase = rf + (size_t)b * CHW_ + (size_t)h * W_;

    f32x4 acc[5];
    #pragma unroll
    for (int i = 0; i < 5; ++i) acc[i] = f32x4{0.f, 0.f, 0.f, 0.f};

    for (int ch = 0; ch < NCHUNK; ++ch) {
        const int c0 = ch * KC;
        if (ch) __syncthreads();   // previous compute must finish before restage

        // ---- stage L chunk: 32 c-pairs x 40 float4 (= KC x LCOLS fp32) ----
        #pragma unroll
        for (int it = 0; it < 3; ++it) {
            int idx = tid + it * 512;
            if (idx < 32 * 40) {
                int rp = idx / 40;            // c pair index
                int q  = idx - rp * 40;       // float4 column
                int w4 = wb + 4 * q;          // global w of first lane elem
                f32x4 v0 = {0.f, 0.f, 0.f, 0.f}, v1 = {0.f, 0.f, 0.f, 0.f};
                if (w4 + 3 < W_) {            // float4-granular by construction
                    const float* g = lbase + (size_t)(c0 + 2 * rp) * HW_ + w4;
                    v0 = *(const f32x4*)g;
                    v1 = *(const f32x4*)(g + HW_);
                }
                const int cc    = 2 * rp;
                const int cbyte = (cc & 7) << 1;
                const int chi   = cc >> 3;
                #pragma unroll
                for (int j = 0; j < 4; ++j) {
                    int lw  = 4 * q + j;
                    int off = lw * PITCH + ((chi ^ (lw & 7)) << 4) + cbyte;
                    *(uint32_t*)(smem + off) = pack2_bf16(v0[j], v1[j]);
                }
            }
        }
        // ---- stage R chunk: 32 c-pairs x 52 float4 (= KC x RCOLS fp32) ----
        #pragma unroll
        for (int it = 0; it < 4; ++it) {
            int idx = tid + it * 512;
            if (idx < 32 * 52) {
                int rp = idx / 52;
                int q  = idx - rp * 52;
                int w4 = wb - 48 + 4 * q;     // can be negative (left edge) -> zeros
                f32x4 v0 = {0.f, 0.f, 0.f, 0.f}, v1 = {0.f, 0.f, 0.f, 0.f};
                if (w4 >= 0 && w4 + 3 < W_) {
                    const float* g = rbase + (size_t)(c0 + 2 * rp) * HW_ + w4;
                    v0 = *(const f32x4*)g;
                    v1 = *(const f32x4*)(g + HW_);
                }
                const int cc    = 2 * rp;
                const int cbyte = (cc & 7) << 1;
                const int chi   = cc >> 3;
                #pragma unroll
                for (int j = 0; j < 4; ++j) {
                    int lw  = 4 * q + j;
                    int off = LBYTES + lw * PITCH + ((chi ^ (lw & 7)) << 4) + cbyte;
                    *(uint32_t*)(smem + off) = pack2_bf16(v0[j], v1[j]);
                }
            }
        }
        __syncthreads();

        // ---- compute: 40 (n,jj) tile-pairs, 5 per wave ----
        // pair p: N-tile n = p>>2 (w = wb+16n+tn), M-tile offset jj = p&3
        //         (w' = wb-48+16(n+jj)+tm), so d = 48 - 16*jj + tn - tm
        #pragma unroll
        for (int ks = 0; ks < 2; ++ks) {
            const int slot = ((ks * 4 + l4) ^ (l15 & 7)) << 4;
            #pragma unroll
            for (int pi = 0; pi < 5; ++pi) {
                const int p   = wave * 5 + pi;
                const int n   = p >> 2;
                const int jj  = p & 3;
                const int lwB = 16 * n + l15;           // L column
                const int lwA = 16 * (n + jj) + l15;    // R column
                bf16x8 afrag = *(const bf16x8*)(smem + LBYTES + lwA * PITCH + slot);
                bf16x8 bfrag = *(const bf16x8*)(smem + lwB * PITCH + slot);
                acc[pi] = __builtin_amdgcn_mfma_f32_16x16x32_bf16(afrag, bfrag, acc[pi], 0, 0, 0);
            }
        }
    }
    __syncthreads();

    // ---- scatter accumulators -> LDS [D_][HALFW] f32 ----
    // D[m][n]: n (col) = l15 = tn, m (row) = 4*l4 + r = tm.
    // w  = wb + 16n + tn ;  w' = wb - 48 + 16(n+jj) + tm
    // d  = w - w' = 48 - 16*jj + tn - tm
    float* outs = (float*)smem;
    #pragma unroll
    for (int pi = 0; pi < 5; ++pi) {
        const int p  = wave * 5 + pi;
        const int n  = p >> 2;
        const int jj = p & 3;
        const int lw = 16 * n + l15;        // tn = l15
        #pragma unroll
        for (int r = 0; r < 4; ++r) {
            int tm = 4 * l4 + r;
            int d  = 48 - 16 * jj + l15 - tm;
            if (d >= 0 && d < D_ && lw < HALFW) {
                outs[d * HALFW + lw] = acc[pi][r] * (1.f / 512.f);
            }
        }
    }
    __syncthreads();

    // ---- coalesced global store ----
    float* obase = out + (size_t)b * (D_ * HW_) + (size_t)h * W_ + wb;
    for (int idx = tid; idx < D_ * HALFW; idx += 512) {
        int d  = idx / HALFW;
        int lw = idx - d * HALFW;
        obase[(size_t)d * HW_ + lw] = outs[idx];
    }
}

extern "C" void kernel_launch(void* const* d_in, const int* in_sizes, int n_in,
                              void* d_out, int out_size, void* d_ws, size_t ws_size,
                              hipStream_t stream) {
    const float* lf = (const float*)d_in[0];
    const float* rf = (const float*)d_in[1];
    float* out = (float*)d_out;
    dim3 grid(2, H_, B_);   // 768 blocks
    psm_cost_volume<<<grid, 512, SMEM_BYTES, stream>>>(lf, rf, out);
}